// Round 1
// 348.388 us; speedup vs baseline: 1.0410x; 1.0410x over previous
//
#include <hip/hip_runtime.h>
#include <math.h>

#define FIN 128   // input features (layer1 K, layer2 K)
#define F1  128   // H1*C1 = layer1 output width
#define C2  64    // layer2 output width
#define NEG 0.2f  // leaky_relu negative slope

#define BKT_SHIFT 8
#define BKT_SIZE  256     // nodes per bucket
#define SCAT_CHUNK 8192   // edges per block in hist/scatter
#define IMGCAP 8192       // LDS csr-image capacity (ints)

typedef _Float16 half4 __attribute__((ext_vector_type(4)));
typedef _Float16 f16x8 __attribute__((ext_vector_type(8)));
typedef _Float16 h2    __attribute__((ext_vector_type(2)));
typedef float    f32x4 __attribute__((ext_vector_type(4)));

union H8u { f16x8 v; h2 p[4]; };

// ================= bucketed CSR build (dst-grouped, self-loops appended) =================
__global__ __launch_bounds__(256) void bucket_hist_kernel(
    const int* __restrict__ ei, int* __restrict__ bcnt, int E, int ET, int NBKT) {
  __shared__ int sh[512];
  const int t = threadIdx.x;
  for (int b = t; b < NBKT; b += 256) sh[b] = 0;
  __syncthreads();
  const int g0 = blockIdx.x * SCAT_CHUNK + t;
#pragma unroll
  for (int i = 0; i < 32; ++i) {
    const int g = g0 + i * 256;
    if (g < ET) {
      const int dst = (g < E) ? ei[E + g] : (g - E);
      atomicAdd(&sh[dst >> BKT_SHIFT], 1);
    }
  }
  __syncthreads();
  for (int b = t; b < NBKT; b += 256)
    if (sh[b]) atomicAdd(&bcnt[b], sh[b]);
}

__global__ __launch_bounds__(512) void bucket_scan_kernel(
    const int* __restrict__ bcnt, int* __restrict__ bbase, int* __restrict__ bcur,
    int* __restrict__ indptr, int NBKT, int N, int ET) {
  __shared__ int sh[512];
  const int t = threadIdx.x;
  const int v = (t < NBKT) ? bcnt[t] : 0;
  sh[t] = v;
  __syncthreads();
  for (int off = 1; off < 512; off <<= 1) {
    int val = (t >= off) ? sh[t - off] : 0;
    __syncthreads();
    sh[t] += val;
    __syncthreads();
  }
  const int excl = sh[t] - v;
  if (t < NBKT) { bbase[t] = excl; bcur[t] = excl; }
  if (t == NBKT - 1) bbase[NBKT] = excl + v;   // == ET
  if (t == 0) indptr[N] = ET;
}

__global__ __launch_bounds__(256) void bucket_scatter_kernel(
    const int* __restrict__ ei, int* __restrict__ bcur, int* __restrict__ tmp,
    int E, int ET, int NBKT) {
  __shared__ int sh_hist[512];
  __shared__ int sh_base[512];
  const int t = threadIdx.x;
  for (int b = t; b < NBKT; b += 256) sh_hist[b] = 0;
  __syncthreads();
  const int g0 = blockIdx.x * SCAT_CHUNK + t;
  int bk[32], pk[32];
#pragma unroll
  for (int i = 0; i < 32; ++i) {
    const int g = g0 + i * 256;
    int b = -1, p = 0;
    if (g < ET) {
      const int src = (g < E) ? ei[g] : (g - E);
      const int dst = (g < E) ? ei[E + g] : (g - E);
      b = dst >> BKT_SHIFT;
      p = (src << BKT_SHIFT) | (dst & (BKT_SIZE - 1));
      atomicAdd(&sh_hist[b], 1);
    }
    bk[i] = b; pk[i] = p;
  }
  __syncthreads();
  for (int b = t; b < NBKT; b += 256) {
    const int c = sh_hist[b];
    sh_base[b] = c ? atomicAdd(&bcur[b], c) : 0;
    sh_hist[b] = 0;   // reuse as in-block cursor
  }
  __syncthreads();
#pragma unroll
  for (int i = 0; i < 32; ++i) {
    if (bk[i] >= 0) {
      const int off = atomicAdd(&sh_hist[bk[i]], 1);
      tmp[sh_base[bk[i]] + off] = pk[i];
    }
  }
}

__global__ __launch_bounds__(256) void build_csr_kernel(
    const int* __restrict__ tmp, const int* __restrict__ bbase,
    int* __restrict__ indptr, int* __restrict__ csr, int N) {
  __shared__ int cnt[256];
  __shared__ int cur[256];
  __shared__ int img[IMGCAP];
  const int b = blockIdx.x;
  const int t = threadIdx.x;
  const int base = bbase[b];
  const int cntb = bbase[b + 1] - base;
  cnt[t] = 0;
  __syncthreads();
  for (int i = t; i < cntb; i += 256)
    atomicAdd(&cnt[tmp[base + i] & (BKT_SIZE - 1)], 1);
  __syncthreads();
  const int v = cnt[t];
  cur[t] = v;
  __syncthreads();
  for (int off = 1; off < 256; off <<= 1) {
    int val = (t >= off) ? cur[t - off] : 0;
    __syncthreads();
    cur[t] += val;
    __syncthreads();
  }
  const int excl = cur[t] - v;
  const int node = (b << BKT_SHIFT) + t;
  if (node < N) indptr[node] = base + excl;
  __syncthreads();
  cur[t] = excl;
  __syncthreads();
  if (cntb <= IMGCAP) {
    for (int i = t; i < cntb; i += 256) {
      const int p = tmp[base + i];
      const int pos = atomicAdd(&cur[p & (BKT_SIZE - 1)], 1);
      img[pos] = p >> BKT_SHIFT;
    }
    __syncthreads();
    for (int i = t; i < cntb; i += 256) csr[base + i] = img[i];
  } else {
    for (int i = t; i < cntb; i += 256) {
      const int p = tmp[base + i];
      const int pos = atomicAdd(&cur[p & (BKT_SIZE - 1)], 1);
      csr[base + pos] = p >> BKT_SHIFT;
    }
  }
}

// ---------------- weight transpose+convert: Wt[n][128] = (fp16) W[k][n] ----------------
__global__ __launch_bounds__(256) void wtrans_kernel(
    const float* __restrict__ W0, const float* __restrict__ W1,
    const float* __restrict__ W2, const float* __restrict__ W3,
    _Float16* __restrict__ T0, _Float16* __restrict__ T1,
    _Float16* __restrict__ T2, _Float16* __restrict__ T3) {
  const int m = blockIdx.y;
  const float* W = (m == 0) ? W0 : (m == 1) ? W1 : (m == 2) ? W2 : W3;
  _Float16* T = (m == 0) ? T0 : (m == 1) ? T1 : (m == 2) ? T2 : T3;
  const int ncols = (m < 2) ? 128 : 64;
  const int idx = blockIdx.x * 256 + threadIdx.x;   // over ncols*128 (n,k)
  if (idx < ncols * 128) {
    const int n = idx >> 7;
    const int k = idx & 127;
    T[idx] = (_Float16)W[k * ncols + n];
  }
}

// ---------------- dual fp16 MFMA GEMM: {OL,OR} = A[M,128] @ {WL,WR}[128,NCOLS] + b ----------------
// Reads A ONCE per row tile, computes both weight products (was 2 kernel passes).
// AF32: A is fp32 (layer-1 input x), converted to f16 fragments in-register -> conv pass deleted.
template<int NCOLS, int CPW, bool AF32>
__global__ __launch_bounds__(256) void gemm_dual_kernel(
    const void* __restrict__ Av,
    const _Float16* __restrict__ WtL, const float* __restrict__ bLp, _Float16* __restrict__ OL,
    const _Float16* __restrict__ WtR, const float* __restrict__ bRp, _Float16* __restrict__ ORp,
    int M) {
  const int wave = threadIdx.x >> 6;
  const int lane = threadIdx.x & 63;
  const int row16 = lane & 15;
  const int quad  = lane >> 4;
  const int kb = quad * 8;
  f16x8 bfL[CPW][4], bfR[CPW][4];
  float bvL[CPW], bvR[CPW];
#pragma unroll
  for (int c = 0; c < CPW; ++c) {
    const int n0 = (wave * CPW + c) * 16;
    bvL[c] = bLp[n0 + row16];
    bvR[c] = bRp[n0 + row16];
#pragma unroll
    for (int kt = 0; kt < 4; ++kt) {
      bfL[c][kt] = *(const f16x8*)(WtL + (n0 + row16) * 128 + kt * 32 + kb);
      bfR[c][kt] = *(const f16x8*)(WtR + (n0 + row16) * 128 + kt * 32 + kb);
    }
  }
  const int rowTiles = (M + 15) >> 4;
  for (int rt = blockIdx.x; rt < rowTiles; rt += gridDim.x) {
    const int r0 = rt << 4;
    const int arow = min(r0 + row16, M - 1);
    f16x8 af[4];
    if constexpr (AF32) {
      const float4* ap = (const float4*)Av + (size_t)arow * 32;
#pragma unroll
      for (int kt = 0; kt < 4; ++kt) {
        const float4 u = ap[kt * 8 + quad * 2];
        const float4 w = ap[kt * 8 + quad * 2 + 1];
        f16x8 h;
        h[0] = (_Float16)u.x; h[1] = (_Float16)u.y;
        h[2] = (_Float16)u.z; h[3] = (_Float16)u.w;
        h[4] = (_Float16)w.x; h[5] = (_Float16)w.y;
        h[6] = (_Float16)w.z; h[7] = (_Float16)w.w;
        af[kt] = h;
      }
    } else {
      const _Float16* A = (const _Float16*)Av;
#pragma unroll
      for (int kt = 0; kt < 4; ++kt)
        af[kt] = *(const f16x8*)(A + (size_t)arow * 128 + kt * 32 + kb);
    }
    f32x4 accL[CPW], accR[CPW];
#pragma unroll
    for (int c = 0; c < CPW; ++c) {
      accL[c] = (f32x4){0.f, 0.f, 0.f, 0.f};
      accR[c] = (f32x4){0.f, 0.f, 0.f, 0.f};
    }
#pragma unroll
    for (int kt = 0; kt < 4; ++kt) {
#pragma unroll
      for (int c = 0; c < CPW; ++c) {
        accL[c] = __builtin_amdgcn_mfma_f32_16x16x32_f16(af[kt], bfL[c][kt], accL[c], 0, 0, 0);
        accR[c] = __builtin_amdgcn_mfma_f32_16x16x32_f16(af[kt], bfR[c][kt], accR[c], 0, 0, 0);
      }
    }
#pragma unroll
    for (int c = 0; c < CPW; ++c) {
      const int col = (wave * CPW + c) * 16 + row16;
#pragma unroll
      for (int r = 0; r < 4; ++r) {
        const int row = r0 + quad * 4 + r;
        if (row < M) {
          OL[(size_t)row * NCOLS + col]  = (_Float16)(accL[c][r] + bvL[c]);
          ORp[(size_t)row * NCOLS + col] = (_Float16)(accR[c][r] + bvR[c]);
        }
      }
    }
  }
}

// ---------------- fused attention helpers: reg-double-buffered 4-edge batches ----------------
// LSH: log2 of row stride in halfs (7 for 128ch, 6 for 64ch).
// Tail indices clamped to end-1 -> duplicate row loads are L1-hits; contributions masked to 0.
template<int LSH>
__device__ __forceinline__ void attn_load4(const _Float16* __restrict__ xlp,
                                           const int* __restrict__ csr,
                                           int e, int endm1,
                                           H8u& x0, H8u& x1, H8u& x2, H8u& x3) {
  const int s0 = csr[min(e,     endm1)];
  const int s1 = csr[min(e + 1, endm1)];
  const int s2 = csr[min(e + 2, endm1)];
  const int s3 = csr[min(e + 3, endm1)];
  x0.v = *(const f16x8*)(xlp + ((size_t)s0 << LSH));
  x1.v = *(const f16x8*)(xlp + ((size_t)s1 << LSH));
  x2.v = *(const f16x8*)(xlp + ((size_t)s2 << LSH));
  x3.v = *(const f16x8*)(xlp + ((size_t)s3 << LSH));
}

// XORS: shfl_xor reduce stages (1 -> 2-lane heads, 3 -> 8-lane head).
// rem in [1,4]; p_i masked to 0 for i >= rem (fold away when rem is literal 4).
template<int XORS>
__device__ __forceinline__ void attn_batch(const H8u& x0, const H8u& x1,
                                           const H8u& x2, const H8u& x3,
                                           const H8u& xru, const H8u& atu,
                                           int rem, float& l, float (&acc)[8]) {
  const h2 neg2 = {(_Float16)NEG, (_Float16)NEG};
  const h2 zero2 = {(_Float16)0.f, (_Float16)0.f};
  h2 sa0 = zero2, sa1 = zero2, sa2 = zero2, sa3 = zero2;
#pragma unroll
  for (int j = 0; j < 4; ++j) {
    h2 e0 = x0.p[j] + xru.p[j];
    h2 e1 = x1.p[j] + xru.p[j];
    h2 e2 = x2.p[j] + xru.p[j];
    h2 e3 = x3.p[j] + xru.p[j];
    e0 = __builtin_elementwise_max(e0, e0 * neg2);
    e1 = __builtin_elementwise_max(e1, e1 * neg2);
    e2 = __builtin_elementwise_max(e2, e2 * neg2);
    e3 = __builtin_elementwise_max(e3, e3 * neg2);
    sa0 = e0 * atu.p[j] + sa0;
    sa1 = e1 * atu.p[j] + sa1;
    sa2 = e2 * atu.p[j] + sa2;
    sa3 = e3 * atu.p[j] + sa3;
  }
  float t0 = (float)sa0[0] + (float)sa0[1];
  float t1 = (float)sa1[0] + (float)sa1[1];
  float t2 = (float)sa2[0] + (float)sa2[1];
  float t3 = (float)sa3[0] + (float)sa3[1];
  t0 += __shfl_xor(t0, 1);  t1 += __shfl_xor(t1, 1);
  t2 += __shfl_xor(t2, 1);  t3 += __shfl_xor(t3, 1);
  if constexpr (XORS >= 2) {
    t0 += __shfl_xor(t0, 2);  t1 += __shfl_xor(t1, 2);
    t2 += __shfl_xor(t2, 2);  t3 += __shfl_xor(t3, 2);
  }
  if constexpr (XORS >= 3) {
    t0 += __shfl_xor(t0, 4);  t1 += __shfl_xor(t1, 4);
    t2 += __shfl_xor(t2, 4);  t3 += __shfl_xor(t3, 4);
  }
  const float p0 = __expf(t0);
  const float p1 = (rem > 1) ? __expf(t1) : 0.f;
  const float p2 = (rem > 2) ? __expf(t2) : 0.f;
  const float p3 = (rem > 3) ? __expf(t3) : 0.f;
  l += (p0 + p1) + (p2 + p3);
#pragma unroll
  for (int j = 0; j < 4; ++j) {
    acc[2*j]   = fmaf(p0, (float)x0.p[j][0], acc[2*j]);
    acc[2*j+1] = fmaf(p0, (float)x0.p[j][1], acc[2*j+1]);
    acc[2*j]   = fmaf(p1, (float)x1.p[j][0], acc[2*j]);
    acc[2*j+1] = fmaf(p1, (float)x1.p[j][1], acc[2*j+1]);
    acc[2*j]   = fmaf(p2, (float)x2.p[j][0], acc[2*j]);
    acc[2*j+1] = fmaf(p2, (float)x2.p[j][1], acc[2*j+1]);
    acc[2*j]   = fmaf(p3, (float)x3.p[j][0], acc[2*j]);
    acc[2*j+1] = fmaf(p3, (float)x3.p[j][1], acc[2*j+1]);
  }
}

// ---------------- layer 1 fused attention: 16 lanes/node x 8 chans, pipelined ----------------
__global__ __launch_bounds__(256) void attn1_kernel(
    const _Float16* __restrict__ xl, const _Float16* __restrict__ xr,
    const float* __restrict__ att, const float* __restrict__ bias,
    const int* __restrict__ indptr, const int* __restrict__ csr,
    _Float16* __restrict__ hout, int N) {
  const int lane = threadIdx.x & 15;
  const int v = blockIdx.x * 16 + (threadIdx.x >> 4);
  if (v >= N) return;
  const int c8 = lane << 3;
  const _Float16* xlp = xl + c8;
  H8u xru; xru.v = *(const f16x8*)(xr + ((size_t)v << 7) + c8);
  H8u atu;
  {
    const float4 a0 = *(const float4*)(att + c8);
    const float4 a1 = *(const float4*)(att + c8 + 4);
    f16x8 a;
    a[0] = (_Float16)a0.x; a[1] = (_Float16)a0.y; a[2] = (_Float16)a0.z; a[3] = (_Float16)a0.w;
    a[4] = (_Float16)a1.x; a[5] = (_Float16)a1.y; a[6] = (_Float16)a1.z; a[7] = (_Float16)a1.w;
    atu.v = a;
  }
  const int beg = indptr[v];
  const int end = indptr[v + 1];
  const int endm1 = end - 1;
  float l = 0.f;
  float acc[8] = {0.f, 0.f, 0.f, 0.f, 0.f, 0.f, 0.f, 0.f};

  H8u a0, a1, a2, a3, b0, b1, b2, b3;
  int e = beg;
  attn_load4<7>(xlp, csr, e, endm1, a0, a1, a2, a3);           // prologue batch
  while (e + 4 < end) {
    attn_load4<7>(xlp, csr, e + 4, endm1, b0, b1, b2, b3);     // prefetch next
    attn_batch<1>(a0, a1, a2, a3, xru, atu, 4, l, acc);        // compute current
    e += 4;
    if (e + 4 < end) {
      attn_load4<7>(xlp, csr, e + 4, endm1, a0, a1, a2, a3);
      attn_batch<1>(b0, b1, b2, b3, xru, atu, 4, l, acc);
      e += 4;
    } else {
      const int rem = end - e;
      attn_batch<1>(b0, b1, b2, b3, xru, atu, rem, l, acc);
      e = end;
      break;
    }
  }
  if (e < end) attn_batch<1>(a0, a1, a2, a3, xru, atu, end - e, l, acc);

  const float rl = 1.f / l;
  const float4 bb0 = *(const float4*)(bias + c8);
  const float4 bb1 = *(const float4*)(bias + c8 + 4);
  float r[8];
  r[0] = fmaf(acc[0], rl, bb0.x); r[1] = fmaf(acc[1], rl, bb0.y);
  r[2] = fmaf(acc[2], rl, bb0.z); r[3] = fmaf(acc[3], rl, bb0.w);
  r[4] = fmaf(acc[4], rl, bb1.x); r[5] = fmaf(acc[5], rl, bb1.y);
  r[6] = fmaf(acc[6], rl, bb1.z); r[7] = fmaf(acc[7], rl, bb1.w);
  f16x8 hres;
#pragma unroll
  for (int i = 0; i < 8; ++i) {
    const float z = r[i] > 0.f ? r[i] : expm1f(r[i]);   // ELU
    hres[i] = (_Float16)z;
  }
  *(f16x8*)(hout + ((size_t)v << 7) + c8) = hres;
}

// ---------------- layer 2 fused attention: 8 lanes/node x 8 chans, pipelined ----------------
__global__ __launch_bounds__(256) void attn2_kernel(
    const _Float16* __restrict__ xl, const _Float16* __restrict__ xr,
    const float* __restrict__ att, const float* __restrict__ bias,
    const int* __restrict__ indptr, const int* __restrict__ csr,
    float* __restrict__ out, int N) {
  const int lane = threadIdx.x & 7;
  const int v = blockIdx.x * 32 + (threadIdx.x >> 3);
  if (v >= N) return;
  const int c8 = lane << 3;
  const _Float16* xlp = xl + c8;
  H8u xru; xru.v = *(const f16x8*)(xr + ((size_t)v << 6) + c8);
  H8u atu;
  {
    const float4 a0 = *(const float4*)(att + c8);
    const float4 a1 = *(const float4*)(att + c8 + 4);
    f16x8 a;
    a[0] = (_Float16)a0.x; a[1] = (_Float16)a0.y; a[2] = (_Float16)a0.z; a[3] = (_Float16)a0.w;
    a[4] = (_Float16)a1.x; a[5] = (_Float16)a1.y; a[6] = (_Float16)a1.z; a[7] = (_Float16)a1.w;
    atu.v = a;
  }
  const int beg = indptr[v];
  const int end = indptr[v + 1];
  const int endm1 = end - 1;
  float l = 0.f;
  float acc[8] = {0.f, 0.f, 0.f, 0.f, 0.f, 0.f, 0.f, 0.f};

  H8u a0, a1, a2, a3, b0, b1, b2, b3;
  int e = beg;
  attn_load4<6>(xlp, csr, e, endm1, a0, a1, a2, a3);
  while (e + 4 < end) {
    attn_load4<6>(xlp, csr, e + 4, endm1, b0, b1, b2, b3);
    attn_batch<3>(a0, a1, a2, a3, xru, atu, 4, l, acc);
    e += 4;
    if (e + 4 < end) {
      attn_load4<6>(xlp, csr, e + 4, endm1, a0, a1, a2, a3);
      attn_batch<3>(b0, b1, b2, b3, xru, atu, 4, l, acc);
      e += 4;
    } else {
      const int rem = end - e;
      attn_batch<3>(b0, b1, b2, b3, xru, atu, rem, l, acc);
      e = end;
      break;
    }
  }
  if (e < end) attn_batch<3>(a0, a1, a2, a3, xru, atu, end - e, l, acc);

  const float rl = 1.f / l;
  const float4 bb0 = *(const float4*)(bias + c8);
  const float4 bb1 = *(const float4*)(bias + c8 + 4);
  float4 o0, o1;
  o0.x = fmaf(acc[0], rl, bb0.x); o0.y = fmaf(acc[1], rl, bb0.y);
  o0.z = fmaf(acc[2], rl, bb0.z); o0.w = fmaf(acc[3], rl, bb0.w);
  o1.x = fmaf(acc[4], rl, bb1.x); o1.y = fmaf(acc[5], rl, bb1.y);
  o1.z = fmaf(acc[6], rl, bb1.z); o1.w = fmaf(acc[7], rl, bb1.w);
  *(float4*)(out + ((size_t)v << 6) + c8) = o0;
  *(float4*)(out + ((size_t)v << 6) + c8 + 4) = o1;
}

extern "C" void kernel_launch(void* const* d_in, const int* in_sizes, int n_in,
                              void* d_out, int out_size, void* d_ws, size_t ws_size,
                              hipStream_t stream) {
  const float* x     = (const float*)d_in[0];
  const int*   ei    = (const int*)d_in[1];
  const float* Wl1   = (const float*)d_in[2];
  const float* bl1   = (const float*)d_in[3];
  const float* Wr1   = (const float*)d_in[4];
  const float* br1   = (const float*)d_in[5];
  const float* att1  = (const float*)d_in[6];
  const float* bias1 = (const float*)d_in[7];
  const float* Wl2   = (const float*)d_in[8];
  const float* bl2   = (const float*)d_in[9];
  const float* Wr2   = (const float*)d_in[10];
  const float* br2   = (const float*)d_in[11];
  const float* att2  = (const float*)d_in[12];
  const float* bias2 = (const float*)d_in[13];

  const int N  = in_sizes[0] / FIN;   // 100000
  const int E  = in_sizes[1] / 2;     // 1600000
  const int ET = E + N;
  const int NBKT = (N + BKT_SIZE - 1) >> BKT_SHIFT;   // 391 (<=512 required)

  // workspace layout (xh eliminated — gemm1 reads x f32 directly)
  _Float16* xl1h  = (_Float16*)d_ws;                   // N*128 f16
  _Float16* xr1h  = xl1h + (size_t)N * F1;             // N*128 f16
  _Float16* hbufh = xr1h + (size_t)N * F1;             // N*128 f16
  _Float16* Wt1l  = hbufh + (size_t)N * F1;            // 128*128 f16
  _Float16* Wt1r  = Wt1l + 128 * 128;
  _Float16* Wt2l  = Wt1r + 128 * 128;                  // 64*128 f16
  _Float16* Wt2r  = Wt2l + 64 * 128;
  int* indptr = (int*)(Wt2r + 64 * 128);               // N+1
  int* csr    = indptr + (N + 1);                      // ET
  int* bcnt   = csr + ET;                              // 512
  int* bbase  = bcnt + 512;                            // 513
  int* bcur   = bbase + 513;                           // 512
  int* tmp    = (int*)hbufh;   // alias: dead before attn1 writes hbufh
  _Float16* xl2h = xl1h;                               // reuse after attn1
  _Float16* xr2h = xr1h;
  float* out  = (float*)d_out;

  const int sblocks = (ET + SCAT_CHUNK - 1) / SCAT_CHUNK;

  hipMemsetAsync(bcnt, 0, 512 * sizeof(int), stream);
  bucket_hist_kernel<<<sblocks, 256, 0, stream>>>(ei, bcnt, E, ET, NBKT);
  bucket_scan_kernel<<<1, 512, 0, stream>>>(bcnt, bbase, bcur, indptr, NBKT, N, ET);
  bucket_scatter_kernel<<<sblocks, 256, 0, stream>>>(ei, bcur, tmp, E, ET, NBKT);
  build_csr_kernel<<<NBKT, 256, 0, stream>>>(tmp, bbase, indptr, csr, N);

  wtrans_kernel<<<dim3(64, 4), 256, 0, stream>>>(Wl1, Wr1, Wl2, Wr2, Wt1l, Wt1r, Wt2l, Wt2r);

  // layer-1 transform: reads f32 x once, produces both xl and xr (f16)
  gemm_dual_kernel<128, 2, true><<<1024, 256, 0, stream>>>(
      x, Wt1l, bl1, xl1h, Wt1r, br1, xr1h, N);

  attn1_kernel<<<(N + 15) / 16, 256, 0, stream>>>(xl1h, xr1h, att1, bias1, indptr, csr, hbufh, N);

  // layer-2 transform: reads h once, produces both xl and xr
  gemm_dual_kernel<64, 1, false><<<1024, 256, 0, stream>>>(
      hbufh, Wt2l, bl2, xl2h, Wt2r, br2, xr2h, N);

  attn2_kernel<<<(N + 31) / 32, 256, 0, stream>>>(xl2h, xr2h, att2, bias2, indptr, csr, out, N);
}

// Round 2
// 342.643 us; speedup vs baseline: 1.0585x; 1.0168x over previous
//
#include <hip/hip_runtime.h>
#include <math.h>

#define FIN 128   // input features (layer1 K, layer2 K)
#define F1  128   // H1*C1 = layer1 output width
#define C2  64    // layer2 output width
#define NEG 0.2f  // leaky_relu negative slope

#define BKT_SHIFT 8
#define BKT_SIZE  256     // nodes per bucket
#define SCAT_CHUNK 8192   // edges per block in hist/scatter
#define IMGCAP 8192       // LDS csr-image capacity (ints)

typedef _Float16 half4 __attribute__((ext_vector_type(4)));
typedef _Float16 f16x8 __attribute__((ext_vector_type(8)));
typedef _Float16 h2    __attribute__((ext_vector_type(2)));
typedef float    f32x4 __attribute__((ext_vector_type(4)));

union H8u { f16x8 v; h2 p[4]; };

#if __has_builtin(__builtin_amdgcn_fdot2)
__device__ __forceinline__ float fdot2_acc(h2 a, h2 b, float c) {
  return __builtin_amdgcn_fdot2(a, b, c, false);
}
#else
__device__ __forceinline__ float fdot2_acc(h2 a, h2 b, float c) {
  return c + (float)a[0] * (float)b[0] + (float)a[1] * (float)b[1];
}
#endif

// ================= bucketed CSR build (dst-grouped, self-loops appended) =================
__global__ __launch_bounds__(256) void bucket_hist_kernel(
    const int* __restrict__ ei, int* __restrict__ bcnt, int E, int ET, int NBKT) {
  __shared__ int sh[512];
  const int t = threadIdx.x;
  for (int b = t; b < NBKT; b += 256) sh[b] = 0;
  __syncthreads();
  const int g0 = blockIdx.x * SCAT_CHUNK + t;
#pragma unroll
  for (int i = 0; i < 32; ++i) {
    const int g = g0 + i * 256;
    if (g < ET) {
      const int dst = (g < E) ? ei[E + g] : (g - E);
      atomicAdd(&sh[dst >> BKT_SHIFT], 1);
    }
  }
  __syncthreads();
  for (int b = t; b < NBKT; b += 256)
    if (sh[b]) atomicAdd(&bcnt[b], sh[b]);
}

__global__ __launch_bounds__(512) void bucket_scan_kernel(
    const int* __restrict__ bcnt, int* __restrict__ bbase, int* __restrict__ bcur,
    int* __restrict__ indptr, int NBKT, int N, int ET) {
  __shared__ int sh[512];
  const int t = threadIdx.x;
  const int v = (t < NBKT) ? bcnt[t] : 0;
  sh[t] = v;
  __syncthreads();
  for (int off = 1; off < 512; off <<= 1) {
    int val = (t >= off) ? sh[t - off] : 0;
    __syncthreads();
    sh[t] += val;
    __syncthreads();
  }
  const int excl = sh[t] - v;
  if (t < NBKT) { bbase[t] = excl; bcur[t] = excl; }
  if (t == NBKT - 1) bbase[NBKT] = excl + v;   // == ET
  if (t == 0) indptr[N] = ET;
}

__global__ __launch_bounds__(256) void bucket_scatter_kernel(
    const int* __restrict__ ei, int* __restrict__ bcur, int* __restrict__ tmp,
    int E, int ET, int NBKT) {
  __shared__ int sh_hist[512];
  __shared__ int sh_base[512];
  const int t = threadIdx.x;
  for (int b = t; b < NBKT; b += 256) sh_hist[b] = 0;
  __syncthreads();
  const int g0 = blockIdx.x * SCAT_CHUNK + t;
  int bk[32], pk[32];
#pragma unroll
  for (int i = 0; i < 32; ++i) {
    const int g = g0 + i * 256;
    int b = -1, p = 0;
    if (g < ET) {
      const int src = (g < E) ? ei[g] : (g - E);
      const int dst = (g < E) ? ei[E + g] : (g - E);
      b = dst >> BKT_SHIFT;
      p = (src << BKT_SHIFT) | (dst & (BKT_SIZE - 1));
      atomicAdd(&sh_hist[b], 1);
    }
    bk[i] = b; pk[i] = p;
  }
  __syncthreads();
  for (int b = t; b < NBKT; b += 256) {
    const int c = sh_hist[b];
    sh_base[b] = c ? atomicAdd(&bcur[b], c) : 0;
    sh_hist[b] = 0;   // reuse as in-block cursor
  }
  __syncthreads();
#pragma unroll
  for (int i = 0; i < 32; ++i) {
    if (bk[i] >= 0) {
      const int off = atomicAdd(&sh_hist[bk[i]], 1);
      tmp[sh_base[bk[i]] + off] = pk[i];
    }
  }
}

__global__ __launch_bounds__(256) void build_csr_kernel(
    const int* __restrict__ tmp, const int* __restrict__ bbase,
    int* __restrict__ indptr, int* __restrict__ csr, int N) {
  __shared__ int cnt[256];
  __shared__ int cur[256];
  __shared__ int img[IMGCAP];
  const int b = blockIdx.x;
  const int t = threadIdx.x;
  const int base = bbase[b];
  const int cntb = bbase[b + 1] - base;
  cnt[t] = 0;
  __syncthreads();
  for (int i = t; i < cntb; i += 256)
    atomicAdd(&cnt[tmp[base + i] & (BKT_SIZE - 1)], 1);
  __syncthreads();
  const int v = cnt[t];
  cur[t] = v;
  __syncthreads();
  for (int off = 1; off < 256; off <<= 1) {
    int val = (t >= off) ? cur[t - off] : 0;
    __syncthreads();
    cur[t] += val;
    __syncthreads();
  }
  const int excl = cur[t] - v;
  const int node = (b << BKT_SHIFT) + t;
  if (node < N) indptr[node] = base + excl;
  __syncthreads();
  cur[t] = excl;
  __syncthreads();
  if (cntb <= IMGCAP) {
    for (int i = t; i < cntb; i += 256) {
      const int p = tmp[base + i];
      const int pos = atomicAdd(&cur[p & (BKT_SIZE - 1)], 1);
      img[pos] = p >> BKT_SHIFT;
    }
    __syncthreads();
    for (int i = t; i < cntb; i += 256) csr[base + i] = img[i];
  } else {
    for (int i = t; i < cntb; i += 256) {
      const int p = tmp[base + i];
      const int pos = atomicAdd(&cur[p & (BKT_SIZE - 1)], 1);
      csr[base + pos] = p >> BKT_SHIFT;
    }
  }
}

// ---------------- weight transpose+convert: Wt[n][128] = (fp16) W[k][n] ----------------
__global__ __launch_bounds__(256) void wtrans_kernel(
    const float* __restrict__ W0, const float* __restrict__ W1,
    const float* __restrict__ W2, const float* __restrict__ W3,
    _Float16* __restrict__ T0, _Float16* __restrict__ T1,
    _Float16* __restrict__ T2, _Float16* __restrict__ T3) {
  const int m = blockIdx.y;
  const float* W = (m == 0) ? W0 : (m == 1) ? W1 : (m == 2) ? W2 : W3;
  _Float16* T = (m == 0) ? T0 : (m == 1) ? T1 : (m == 2) ? T2 : T3;
  const int ncols = (m < 2) ? 128 : 64;
  const int idx = blockIdx.x * 256 + threadIdx.x;   // over ncols*128 (n,k)
  if (idx < ncols * 128) {
    const int n = idx >> 7;
    const int k = idx & 127;
    T[idx] = (_Float16)W[k * ncols + n];
  }
}

// ---------------- dual fp16 MFMA GEMM: {OL,OR} = A[M,128] @ {WL,WR}[128,NCOLS] + b ----------------
// Reads A ONCE per row tile, computes both weight products.
// AF32: A is fp32 (layer-1 input x), converted to f16 fragments in-register.
template<int NCOLS, int CPW, bool AF32>
__global__ __launch_bounds__(256) void gemm_dual_kernel(
    const void* __restrict__ Av,
    const _Float16* __restrict__ WtL, const float* __restrict__ bLp, _Float16* __restrict__ OL,
    const _Float16* __restrict__ WtR, const float* __restrict__ bRp, _Float16* __restrict__ ORp,
    int M) {
  const int wave = threadIdx.x >> 6;
  const int lane = threadIdx.x & 63;
  const int row16 = lane & 15;
  const int quad  = lane >> 4;
  const int kb = quad * 8;
  f16x8 bfL[CPW][4], bfR[CPW][4];
  float bvL[CPW], bvR[CPW];
#pragma unroll
  for (int c = 0; c < CPW; ++c) {
    const int n0 = (wave * CPW + c) * 16;
    bvL[c] = bLp[n0 + row16];
    bvR[c] = bRp[n0 + row16];
#pragma unroll
    for (int kt = 0; kt < 4; ++kt) {
      bfL[c][kt] = *(const f16x8*)(WtL + (n0 + row16) * 128 + kt * 32 + kb);
      bfR[c][kt] = *(const f16x8*)(WtR + (n0 + row16) * 128 + kt * 32 + kb);
    }
  }
  const int rowTiles = (M + 15) >> 4;
  for (int rt = blockIdx.x; rt < rowTiles; rt += gridDim.x) {
    const int r0 = rt << 4;
    const int arow = min(r0 + row16, M - 1);
    f16x8 af[4];
    if constexpr (AF32) {
      const float4* ap = (const float4*)Av + (size_t)arow * 32;
#pragma unroll
      for (int kt = 0; kt < 4; ++kt) {
        const float4 u = ap[kt * 8 + quad * 2];
        const float4 w = ap[kt * 8 + quad * 2 + 1];
        f16x8 h;
        h[0] = (_Float16)u.x; h[1] = (_Float16)u.y;
        h[2] = (_Float16)u.z; h[3] = (_Float16)u.w;
        h[4] = (_Float16)w.x; h[5] = (_Float16)w.y;
        h[6] = (_Float16)w.z; h[7] = (_Float16)w.w;
        af[kt] = h;
      }
    } else {
      const _Float16* A = (const _Float16*)Av;
#pragma unroll
      for (int kt = 0; kt < 4; ++kt)
        af[kt] = *(const f16x8*)(A + (size_t)arow * 128 + kt * 32 + kb);
    }
    f32x4 accL[CPW], accR[CPW];
#pragma unroll
    for (int c = 0; c < CPW; ++c) {
      accL[c] = (f32x4){0.f, 0.f, 0.f, 0.f};
      accR[c] = (f32x4){0.f, 0.f, 0.f, 0.f};
    }
#pragma unroll
    for (int kt = 0; kt < 4; ++kt) {
#pragma unroll
      for (int c = 0; c < CPW; ++c) {
        accL[c] = __builtin_amdgcn_mfma_f32_16x16x32_f16(af[kt], bfL[c][kt], accL[c], 0, 0, 0);
        accR[c] = __builtin_amdgcn_mfma_f32_16x16x32_f16(af[kt], bfR[c][kt], accR[c], 0, 0, 0);
      }
    }
#pragma unroll
    for (int c = 0; c < CPW; ++c) {
      const int col = (wave * CPW + c) * 16 + row16;
#pragma unroll
      for (int r = 0; r < 4; ++r) {
        const int row = r0 + quad * 4 + r;
        if (row < M) {
          OL[(size_t)row * NCOLS + col]  = (_Float16)(accL[c][r] + bvL[c]);
          ORp[(size_t)row * NCOLS + col] = (_Float16)(accR[c][r] + bvR[c]);
        }
      }
    }
  }
}

// ---------------- attention batch: B independent gathers in flight, no masking ----------------
// LSH: log2 row stride in halfs (7 -> 128ch, 6 -> 64ch). XORS: shfl reduce stages.
// All array indices resolve statically under full unroll (no scratch).
template<int LSH, int XORS, int B>
__device__ __forceinline__ void attn_block(const _Float16* __restrict__ xlp,
                                           const int* __restrict__ csr, int e,
                                           const H8u& xru, const H8u& atu,
                                           float& l, float (&acc)[8]) {
  const h2 neg2 = {(_Float16)NEG, (_Float16)NEG};
  int s[B];
#pragma unroll
  for (int i = 0; i < B; ++i) s[i] = csr[e + i];
  H8u x[B];
#pragma unroll
  for (int i = 0; i < B; ++i) x[i].v = *(const f16x8*)(xlp + ((size_t)s[i] << LSH));
  float t[B];
#pragma unroll
  for (int i = 0; i < B; ++i) {
    float tv = 0.f;
#pragma unroll
    for (int j = 0; j < 4; ++j) {
      h2 ev = x[i].p[j] + xru.p[j];
      ev = __builtin_elementwise_max(ev, ev * neg2);
      tv = fdot2_acc(ev, atu.p[j], tv);
    }
    t[i] = tv;
  }
#pragma unroll
  for (int i = 0; i < B; ++i) {
    t[i] += __shfl_xor(t[i], 1);
    if constexpr (XORS >= 2) t[i] += __shfl_xor(t[i], 2);
    if constexpr (XORS >= 3) t[i] += __shfl_xor(t[i], 4);
  }
  float p[B];
#pragma unroll
  for (int i = 0; i < B; ++i) { p[i] = __expf(t[i]); l += p[i]; }
#pragma unroll
  for (int i = 0; i < B; ++i) {
#pragma unroll
    for (int j = 0; j < 4; ++j) {
      acc[2*j]   = fmaf(p[i], (float)x[i].p[j][0], acc[2*j]);
      acc[2*j+1] = fmaf(p[i], (float)x[i].p[j][1], acc[2*j+1]);
    }
  }
}

template<int LSH, int XORS>
__device__ __forceinline__ void attn_edges(const _Float16* __restrict__ xlp,
                                           const int* __restrict__ csr,
                                           int beg, int end,
                                           const H8u& xru, const H8u& atu,
                                           float& l, float (&acc)[8]) {
  int e = beg;
  for (; e + 8 <= end; e += 8) attn_block<LSH, XORS, 8>(xlp, csr, e, xru, atu, l, acc);
  if (e + 4 <= end) { attn_block<LSH, XORS, 4>(xlp, csr, e, xru, atu, l, acc); e += 4; }
  if (e + 2 <= end) { attn_block<LSH, XORS, 2>(xlp, csr, e, xru, atu, l, acc); e += 2; }
  if (e < end)      { attn_block<LSH, XORS, 1>(xlp, csr, e, xru, atu, l, acc); }
}

// ---------------- layer 1 fused attention: 16 lanes/node x 8 chans ----------------
__global__ __launch_bounds__(256) void attn1_kernel(
    const _Float16* __restrict__ xl, const _Float16* __restrict__ xr,
    const float* __restrict__ att, const float* __restrict__ bias,
    const int* __restrict__ indptr, const int* __restrict__ csr,
    _Float16* __restrict__ hout, int N) {
  const int lane = threadIdx.x & 15;
  const int v = blockIdx.x * 16 + (threadIdx.x >> 4);
  if (v >= N) return;
  const int c8 = lane << 3;
  const _Float16* xlp = xl + c8;
  H8u xru; xru.v = *(const f16x8*)(xr + ((size_t)v << 7) + c8);
  H8u atu;
  {
    const float4 a0 = *(const float4*)(att + c8);
    const float4 a1 = *(const float4*)(att + c8 + 4);
    f16x8 a;
    a[0] = (_Float16)a0.x; a[1] = (_Float16)a0.y; a[2] = (_Float16)a0.z; a[3] = (_Float16)a0.w;
    a[4] = (_Float16)a1.x; a[5] = (_Float16)a1.y; a[6] = (_Float16)a1.z; a[7] = (_Float16)a1.w;
    atu.v = a;
  }
  const int beg = indptr[v];
  const int end = indptr[v + 1];
  float l = 0.f;
  float acc[8] = {0.f, 0.f, 0.f, 0.f, 0.f, 0.f, 0.f, 0.f};
  attn_edges<7, 1>(xlp, csr, beg, end, xru, atu, l, acc);

  const float rl = 1.f / l;
  const float4 bb0 = *(const float4*)(bias + c8);
  const float4 bb1 = *(const float4*)(bias + c8 + 4);
  float r[8];
  r[0] = fmaf(acc[0], rl, bb0.x); r[1] = fmaf(acc[1], rl, bb0.y);
  r[2] = fmaf(acc[2], rl, bb0.z); r[3] = fmaf(acc[3], rl, bb0.w);
  r[4] = fmaf(acc[4], rl, bb1.x); r[5] = fmaf(acc[5], rl, bb1.y);
  r[6] = fmaf(acc[6], rl, bb1.z); r[7] = fmaf(acc[7], rl, bb1.w);
  f16x8 hres;
#pragma unroll
  for (int i = 0; i < 8; ++i) {
    const float z = r[i] > 0.f ? r[i] : expm1f(r[i]);   // ELU
    hres[i] = (_Float16)z;
  }
  *(f16x8*)(hout + ((size_t)v << 7) + c8) = hres;
}

// ---------------- layer 2 fused attention: 8 lanes/node x 8 chans ----------------
__global__ __launch_bounds__(256) void attn2_kernel(
    const _Float16* __restrict__ xl, const _Float16* __restrict__ xr,
    const float* __restrict__ att, const float* __restrict__ bias,
    const int* __restrict__ indptr, const int* __restrict__ csr,
    float* __restrict__ out, int N) {
  const int lane = threadIdx.x & 7;
  const int v = blockIdx.x * 32 + (threadIdx.x >> 3);
  if (v >= N) return;
  const int c8 = lane << 3;
  const _Float16* xlp = xl + c8;
  H8u xru; xru.v = *(const f16x8*)(xr + ((size_t)v << 6) + c8);
  H8u atu;
  {
    const float4 a0 = *(const float4*)(att + c8);
    const float4 a1 = *(const float4*)(att + c8 + 4);
    f16x8 a;
    a[0] = (_Float16)a0.x; a[1] = (_Float16)a0.y; a[2] = (_Float16)a0.z; a[3] = (_Float16)a0.w;
    a[4] = (_Float16)a1.x; a[5] = (_Float16)a1.y; a[6] = (_Float16)a1.z; a[7] = (_Float16)a1.w;
    atu.v = a;
  }
  const int beg = indptr[v];
  const int end = indptr[v + 1];
  float l = 0.f;
  float acc[8] = {0.f, 0.f, 0.f, 0.f, 0.f, 0.f, 0.f, 0.f};
  attn_edges<6, 3>(xlp, csr, beg, end, xru, atu, l, acc);

  const float rl = 1.f / l;
  const float4 bb0 = *(const float4*)(bias + c8);
  const float4 bb1 = *(const float4*)(bias + c8 + 4);
  float4 o0, o1;
  o0.x = fmaf(acc[0], rl, bb0.x); o0.y = fmaf(acc[1], rl, bb0.y);
  o0.z = fmaf(acc[2], rl, bb0.z); o0.w = fmaf(acc[3], rl, bb0.w);
  o1.x = fmaf(acc[4], rl, bb1.x); o1.y = fmaf(acc[5], rl, bb1.y);
  o1.z = fmaf(acc[6], rl, bb1.z); o1.w = fmaf(acc[7], rl, bb1.w);
  *(float4*)(out + ((size_t)v << 6) + c8) = o0;
  *(float4*)(out + ((size_t)v << 6) + c8 + 4) = o1;
}

extern "C" void kernel_launch(void* const* d_in, const int* in_sizes, int n_in,
                              void* d_out, int out_size, void* d_ws, size_t ws_size,
                              hipStream_t stream) {
  const float* x     = (const float*)d_in[0];
  const int*   ei    = (const int*)d_in[1];
  const float* Wl1   = (const float*)d_in[2];
  const float* bl1   = (const float*)d_in[3];
  const float* Wr1   = (const float*)d_in[4];
  const float* br1   = (const float*)d_in[5];
  const float* att1  = (const float*)d_in[6];
  const float* bias1 = (const float*)d_in[7];
  const float* Wl2   = (const float*)d_in[8];
  const float* bl2   = (const float*)d_in[9];
  const float* Wr2   = (const float*)d_in[10];
  const float* br2   = (const float*)d_in[11];
  const float* att2  = (const float*)d_in[12];
  const float* bias2 = (const float*)d_in[13];

  const int N  = in_sizes[0] / FIN;   // 100000
  const int E  = in_sizes[1] / 2;     // 1600000
  const int ET = E + N;
  const int NBKT = (N + BKT_SIZE - 1) >> BKT_SHIFT;   // 391 (<=512 required)

  // workspace layout (xh eliminated — gemm1 reads x f32 directly)
  _Float16* xl1h  = (_Float16*)d_ws;                   // N*128 f16
  _Float16* xr1h  = xl1h + (size_t)N * F1;             // N*128 f16
  _Float16* hbufh = xr1h + (size_t)N * F1;             // N*128 f16
  _Float16* Wt1l  = hbufh + (size_t)N * F1;            // 128*128 f16
  _Float16* Wt1r  = Wt1l + 128 * 128;
  _Float16* Wt2l  = Wt1r + 128 * 128;                  // 64*128 f16
  _Float16* Wt2r  = Wt2l + 64 * 128;
  int* indptr = (int*)(Wt2r + 64 * 128);               // N+1
  int* csr    = indptr + (N + 1);                      // ET
  int* bcnt   = csr + ET;                              // 512
  int* bbase  = bcnt + 512;                            // 513
  int* bcur   = bbase + 513;                           // 512
  int* tmp    = (int*)hbufh;   // alias: dead before attn1 writes hbufh
  _Float16* xl2h = xl1h;                               // reuse after attn1
  _Float16* xr2h = xr1h;
  float* out  = (float*)d_out;

  const int sblocks = (ET + SCAT_CHUNK - 1) / SCAT_CHUNK;

  hipMemsetAsync(bcnt, 0, 512 * sizeof(int), stream);
  bucket_hist_kernel<<<sblocks, 256, 0, stream>>>(ei, bcnt, E, ET, NBKT);
  bucket_scan_kernel<<<1, 512, 0, stream>>>(bcnt, bbase, bcur, indptr, NBKT, N, ET);
  bucket_scatter_kernel<<<sblocks, 256, 0, stream>>>(ei, bcur, tmp, E, ET, NBKT);
  build_csr_kernel<<<NBKT, 256, 0, stream>>>(tmp, bbase, indptr, csr, N);

  wtrans_kernel<<<dim3(64, 4), 256, 0, stream>>>(Wl1, Wr1, Wl2, Wr2, Wt1l, Wt1r, Wt2l, Wt2r);

  // layer-1 transform: reads f32 x once, produces both xl and xr (f16)
  gemm_dual_kernel<128, 2, true><<<1024, 256, 0, stream>>>(
      x, Wt1l, bl1, xl1h, Wt1r, br1, xr1h, N);

  attn1_kernel<<<(N + 15) / 16, 256, 0, stream>>>(xl1h, xr1h, att1, bias1, indptr, csr, hbufh, N);

  // layer-2 transform: reads h once, produces both xl and xr
  gemm_dual_kernel<64, 1, false><<<1024, 256, 0, stream>>>(
      hbufh, Wt2l, bl2, xl2h, Wt2r, br2, xr2h, N);

  attn2_kernel<<<(N + 31) / 32, 256, 0, stream>>>(xl2h, xr2h, att2, bias2, indptr, csr, out, N);
}

// Round 3
// 318.598 us; speedup vs baseline: 1.1384x; 1.0755x over previous
//
#include <hip/hip_runtime.h>
#include <math.h>

#define FIN 128   // input features (layer1 K, layer2 K)
#define F1  128   // H1*C1 = layer1 output width
#define C2  64    // layer2 output width
#define NEG 0.2f  // leaky_relu negative slope

#define BKT_SHIFT 8
#define BKT_SIZE  256     // nodes per bucket
#define BKT_CAP   5120    // fixed slots per bucket (mean 4348, sigma 66 -> P(overflow)~1e-31)
#define SCAT_CHUNK 8192   // edges per block in scatter
#define IMGCAP 8192       // LDS csr-image capacity (ints)

typedef _Float16 half4 __attribute__((ext_vector_type(4)));
typedef _Float16 f16x8 __attribute__((ext_vector_type(8)));
typedef _Float16 h2    __attribute__((ext_vector_type(2)));
typedef float    f32x4 __attribute__((ext_vector_type(4)));

union H8u { f16x8 v; h2 p[4]; };

#if __has_builtin(__builtin_amdgcn_fdot2)
__device__ __forceinline__ float fdot2_acc(h2 a, h2 b, float c) {
  return __builtin_amdgcn_fdot2(a, b, c, false);
}
#else
__device__ __forceinline__ float fdot2_acc(h2 a, h2 b, float c) {
  return c + (float)a[0] * (float)b[0] + (float)a[1] * (float)b[1];
}
#endif

// ================= bucketed CSR build (dst-grouped, fixed-capacity buckets) =================
// One pass: LDS histogram -> per-bucket global reservation at b*BKT_CAP -> scatter.
__global__ __launch_bounds__(256) void bucket_scatter_kernel(
    const int* __restrict__ ei, int* __restrict__ bcur, int* __restrict__ tmp,
    int E, int ET, int NBKT) {
  __shared__ int sh_hist[512];
  __shared__ int sh_base[512];
  const int t = threadIdx.x;
  for (int b = t; b < NBKT; b += 256) sh_hist[b] = 0;
  __syncthreads();
  const int g0 = blockIdx.x * SCAT_CHUNK + t;
  int bk[32], pk[32];
#pragma unroll
  for (int i = 0; i < 32; ++i) {
    const int g = g0 + i * 256;
    int b = -1, p = 0;
    if (g < ET) {
      const int src = (g < E) ? ei[g] : (g - E);
      const int dst = (g < E) ? ei[E + g] : (g - E);
      b = dst >> BKT_SHIFT;
      p = (src << BKT_SHIFT) | (dst & (BKT_SIZE - 1));
      atomicAdd(&sh_hist[b], 1);
    }
    bk[i] = b; pk[i] = p;
  }
  __syncthreads();
  for (int b = t; b < NBKT; b += 256) {
    const int c = sh_hist[b];
    sh_base[b] = c ? (b * BKT_CAP + atomicAdd(&bcur[b], c)) : 0;
    sh_hist[b] = 0;   // reuse as in-block cursor
  }
  __syncthreads();
#pragma unroll
  for (int i = 0; i < 32; ++i) {
    if (bk[i] >= 0) {
      const int off = atomicAdd(&sh_hist[bk[i]], 1);
      tmp[sh_base[bk[i]] + off] = pk[i];
    }
  }
}

// Per-bucket: sort by dst-local (counting sort), emit per-node {beg,end} extents.
__global__ __launch_bounds__(256) void build_csr_kernel(
    const int* __restrict__ tmp, const int* __restrict__ bcnt,
    int2* __restrict__ ind2, int* __restrict__ csr, int N) {
  __shared__ int cnt[256];
  __shared__ int cur[256];
  __shared__ int img[IMGCAP];
  const int b = blockIdx.x;
  const int t = threadIdx.x;
  const int base = b * BKT_CAP;
  const int cntb = bcnt[b];
  cnt[t] = 0;
  __syncthreads();
  for (int i = t; i < cntb; i += 256)
    atomicAdd(&cnt[tmp[base + i] & (BKT_SIZE - 1)], 1);
  __syncthreads();
  const int v = cnt[t];
  cur[t] = v;
  __syncthreads();
  for (int off = 1; off < 256; off <<= 1) {
    int val = (t >= off) ? cur[t - off] : 0;
    __syncthreads();
    cur[t] += val;
    __syncthreads();
  }
  const int excl = cur[t] - v;
  const int node = (b << BKT_SHIFT) + t;
  if (node < N) ind2[node] = make_int2(base + excl, base + excl + v);
  __syncthreads();
  cur[t] = excl;
  __syncthreads();
  if (cntb <= IMGCAP) {
    for (int i = t; i < cntb; i += 256) {
      const int p = tmp[base + i];
      const int pos = atomicAdd(&cur[p & (BKT_SIZE - 1)], 1);
      img[pos] = p >> BKT_SHIFT;
    }
    __syncthreads();
    for (int i = t; i < cntb; i += 256) csr[base + i] = img[i];
  } else {
    for (int i = t; i < cntb; i += 256) {
      const int p = tmp[base + i];
      const int pos = atomicAdd(&cur[p & (BKT_SIZE - 1)], 1);
      csr[base + pos] = p >> BKT_SHIFT;
    }
  }
}

// ---------------- weight transpose+convert: Wt[n][128] = (fp16) W[k][n] ----------------
__global__ __launch_bounds__(256) void wtrans_kernel(
    const float* __restrict__ W0, const float* __restrict__ W1,
    const float* __restrict__ W2, const float* __restrict__ W3,
    _Float16* __restrict__ T0, _Float16* __restrict__ T1,
    _Float16* __restrict__ T2, _Float16* __restrict__ T3) {
  const int m = blockIdx.y;
  const float* W = (m == 0) ? W0 : (m == 1) ? W1 : (m == 2) ? W2 : W3;
  _Float16* T = (m == 0) ? T0 : (m == 1) ? T1 : (m == 2) ? T2 : T3;
  const int ncols = (m < 2) ? 128 : 64;
  const int idx = blockIdx.x * 256 + threadIdx.x;   // over ncols*128 (n,k)
  if (idx < ncols * 128) {
    const int n = idx >> 7;
    const int k = idx & 127;
    T[idx] = (_Float16)W[k * ncols + n];
  }
}

// ---------------- dual fp16 MFMA GEMM: {OL,OR} = A[M,128] @ {WL,WR}[128,NCOLS] + b ----------------
// Reads A ONCE per row tile, computes both weight products.
// AF32: A is fp32 (layer-1 input x), converted to f16 fragments in-register.
template<int NCOLS, int CPW, bool AF32>
__global__ __launch_bounds__(256) void gemm_dual_kernel(
    const void* __restrict__ Av,
    const _Float16* __restrict__ WtL, const float* __restrict__ bLp, _Float16* __restrict__ OL,
    const _Float16* __restrict__ WtR, const float* __restrict__ bRp, _Float16* __restrict__ ORp,
    int M) {
  const int wave = threadIdx.x >> 6;
  const int lane = threadIdx.x & 63;
  const int row16 = lane & 15;
  const int quad  = lane >> 4;
  const int kb = quad * 8;
  f16x8 bfL[CPW][4], bfR[CPW][4];
  float bvL[CPW], bvR[CPW];
#pragma unroll
  for (int c = 0; c < CPW; ++c) {
    const int n0 = (wave * CPW + c) * 16;
    bvL[c] = bLp[n0 + row16];
    bvR[c] = bRp[n0 + row16];
#pragma unroll
    for (int kt = 0; kt < 4; ++kt) {
      bfL[c][kt] = *(const f16x8*)(WtL + (n0 + row16) * 128 + kt * 32 + kb);
      bfR[c][kt] = *(const f16x8*)(WtR + (n0 + row16) * 128 + kt * 32 + kb);
    }
  }
  const int rowTiles = (M + 15) >> 4;
  for (int rt = blockIdx.x; rt < rowTiles; rt += gridDim.x) {
    const int r0 = rt << 4;
    const int arow = min(r0 + row16, M - 1);
    f16x8 af[4];
    if constexpr (AF32) {
      const float4* ap = (const float4*)Av + (size_t)arow * 32;
#pragma unroll
      for (int kt = 0; kt < 4; ++kt) {
        const float4 u = ap[kt * 8 + quad * 2];
        const float4 w = ap[kt * 8 + quad * 2 + 1];
        f16x8 h;
        h[0] = (_Float16)u.x; h[1] = (_Float16)u.y;
        h[2] = (_Float16)u.z; h[3] = (_Float16)u.w;
        h[4] = (_Float16)w.x; h[5] = (_Float16)w.y;
        h[6] = (_Float16)w.z; h[7] = (_Float16)w.w;
        af[kt] = h;
      }
    } else {
      const _Float16* A = (const _Float16*)Av;
#pragma unroll
      for (int kt = 0; kt < 4; ++kt)
        af[kt] = *(const f16x8*)(A + (size_t)arow * 128 + kt * 32 + kb);
    }
    f32x4 accL[CPW], accR[CPW];
#pragma unroll
    for (int c = 0; c < CPW; ++c) {
      accL[c] = (f32x4){0.f, 0.f, 0.f, 0.f};
      accR[c] = (f32x4){0.f, 0.f, 0.f, 0.f};
    }
#pragma unroll
    for (int kt = 0; kt < 4; ++kt) {
#pragma unroll
      for (int c = 0; c < CPW; ++c) {
        accL[c] = __builtin_amdgcn_mfma_f32_16x16x32_f16(af[kt], bfL[c][kt], accL[c], 0, 0, 0);
        accR[c] = __builtin_amdgcn_mfma_f32_16x16x32_f16(af[kt], bfR[c][kt], accR[c], 0, 0, 0);
      }
    }
#pragma unroll
    for (int c = 0; c < CPW; ++c) {
      const int col = (wave * CPW + c) * 16 + row16;
#pragma unroll
      for (int r = 0; r < 4; ++r) {
        const int row = r0 + quad * 4 + r;
        if (row < M) {
          OL[(size_t)row * NCOLS + col]  = (_Float16)(accL[c][r] + bvL[c]);
          ORp[(size_t)row * NCOLS + col] = (_Float16)(accR[c][r] + bvR[c]);
        }
      }
    }
  }
}

// ---------------- attention batch: B gathers issued together, then compute ----------------
// LSH: log2 row stride in halfs (7 -> 128ch, 6 -> 64ch). XORS: shfl reduce stages.
template<int LSH, int XORS, int B>
__device__ __forceinline__ void attn_block(const _Float16* __restrict__ xlp,
                                           const int* __restrict__ csr, int e,
                                           const H8u& xru, const H8u& atu,
                                           float& l, float (&acc)[8]) {
  const h2 neg2 = {(_Float16)NEG, (_Float16)NEG};
  int s[B];
#pragma unroll
  for (int i = 0; i < B; ++i) s[i] = csr[e + i];
  H8u x[B];
#pragma unroll
  for (int i = 0; i < B; ++i) x[i].v = *(const f16x8*)(xlp + ((size_t)s[i] << LSH));
  float t[B];
#pragma unroll
  for (int i = 0; i < B; ++i) {
    float tv = 0.f;
#pragma unroll
    for (int j = 0; j < 4; ++j) {
      h2 ev = x[i].p[j] + xru.p[j];
      ev = __builtin_elementwise_max(ev, ev * neg2);
      tv = fdot2_acc(ev, atu.p[j], tv);
    }
    t[i] = tv;
  }
#pragma unroll
  for (int i = 0; i < B; ++i) {
    t[i] += __shfl_xor(t[i], 1);
    if constexpr (XORS >= 2) t[i] += __shfl_xor(t[i], 2);
    if constexpr (XORS >= 3) t[i] += __shfl_xor(t[i], 4);
  }
  float p[B];
#pragma unroll
  for (int i = 0; i < B; ++i) { p[i] = __expf(t[i]); l += p[i]; }
#pragma unroll
  for (int i = 0; i < B; ++i) {
#pragma unroll
    for (int j = 0; j < 4; ++j) {
      acc[2*j]   = fmaf(p[i], (float)x[i].p[j][0], acc[2*j]);
      acc[2*j+1] = fmaf(p[i], (float)x[i].p[j][1], acc[2*j+1]);
    }
  }
}

template<int LSH, int XORS>
__device__ __forceinline__ void attn_edges(const _Float16* __restrict__ xlp,
                                           const int* __restrict__ csr,
                                           int beg, int end,
                                           const H8u& xru, const H8u& atu,
                                           float& l, float (&acc)[8]) {
  int e = beg;
  for (; e + 4 <= end; e += 4) attn_block<LSH, XORS, 4>(xlp, csr, e, xru, atu, l, acc);
  if (e + 2 <= end) { attn_block<LSH, XORS, 2>(xlp, csr, e, xru, atu, l, acc); e += 2; }
  if (e < end)      { attn_block<LSH, XORS, 1>(xlp, csr, e, xru, atu, l, acc); }
}

// ---------------- layer 1 fused attention: 16 lanes/node x 8 chans ----------------
__global__ __launch_bounds__(256) void attn1_kernel(
    const _Float16* __restrict__ xl, const _Float16* __restrict__ xr,
    const float* __restrict__ att, const float* __restrict__ bias,
    const int2* __restrict__ ind2, const int* __restrict__ csr,
    _Float16* __restrict__ hout, int N) {
  const int lane = threadIdx.x & 15;
  const int v = blockIdx.x * 16 + (threadIdx.x >> 4);
  if (v >= N) return;
  const int c8 = lane << 3;
  const _Float16* xlp = xl + c8;
  H8u xru; xru.v = *(const f16x8*)(xr + ((size_t)v << 7) + c8);
  H8u atu;
  {
    const float4 a0 = *(const float4*)(att + c8);
    const float4 a1 = *(const float4*)(att + c8 + 4);
    f16x8 a;
    a[0] = (_Float16)a0.x; a[1] = (_Float16)a0.y; a[2] = (_Float16)a0.z; a[3] = (_Float16)a0.w;
    a[4] = (_Float16)a1.x; a[5] = (_Float16)a1.y; a[6] = (_Float16)a1.z; a[7] = (_Float16)a1.w;
    atu.v = a;
  }
  const int2 be = ind2[v];
  const int beg = be.x;
  const int end = be.y;
  float l = 0.f;
  float acc[8] = {0.f, 0.f, 0.f, 0.f, 0.f, 0.f, 0.f, 0.f};
  attn_edges<7, 1>(xlp, csr, beg, end, xru, atu, l, acc);

  const float rl = 1.f / l;
  const float4 bb0 = *(const float4*)(bias + c8);
  const float4 bb1 = *(const float4*)(bias + c8 + 4);
  float r[8];
  r[0] = fmaf(acc[0], rl, bb0.x); r[1] = fmaf(acc[1], rl, bb0.y);
  r[2] = fmaf(acc[2], rl, bb0.z); r[3] = fmaf(acc[3], rl, bb0.w);
  r[4] = fmaf(acc[4], rl, bb1.x); r[5] = fmaf(acc[5], rl, bb1.y);
  r[6] = fmaf(acc[6], rl, bb1.z); r[7] = fmaf(acc[7], rl, bb1.w);
  f16x8 hres;
#pragma unroll
  for (int i = 0; i < 8; ++i) {
    const float z = r[i] > 0.f ? r[i] : expm1f(r[i]);   // ELU
    hres[i] = (_Float16)z;
  }
  *(f16x8*)(hout + ((size_t)v << 7) + c8) = hres;
}

// ---------------- layer 2 fused attention: 8 lanes/node x 8 chans ----------------
__global__ __launch_bounds__(256) void attn2_kernel(
    const _Float16* __restrict__ xl, const _Float16* __restrict__ xr,
    const float* __restrict__ att, const float* __restrict__ bias,
    const int2* __restrict__ ind2, const int* __restrict__ csr,
    float* __restrict__ out, int N) {
  const int lane = threadIdx.x & 7;
  const int v = blockIdx.x * 32 + (threadIdx.x >> 3);
  if (v >= N) return;
  const int c8 = lane << 3;
  const _Float16* xlp = xl + c8;
  H8u xru; xru.v = *(const f16x8*)(xr + ((size_t)v << 6) + c8);
  H8u atu;
  {
    const float4 a0 = *(const float4*)(att + c8);
    const float4 a1 = *(const float4*)(att + c8 + 4);
    f16x8 a;
    a[0] = (_Float16)a0.x; a[1] = (_Float16)a0.y; a[2] = (_Float16)a0.z; a[3] = (_Float16)a0.w;
    a[4] = (_Float16)a1.x; a[5] = (_Float16)a1.y; a[6] = (_Float16)a1.z; a[7] = (_Float16)a1.w;
    atu.v = a;
  }
  const int2 be = ind2[v];
  const int beg = be.x;
  const int end = be.y;
  float l = 0.f;
  float acc[8] = {0.f, 0.f, 0.f, 0.f, 0.f, 0.f, 0.f, 0.f};
  attn_edges<6, 3>(xlp, csr, beg, end, xru, atu, l, acc);

  const float rl = 1.f / l;
  const float4 bb0 = *(const float4*)(bias + c8);
  const float4 bb1 = *(const float4*)(bias + c8 + 4);
  float4 o0, o1;
  o0.x = fmaf(acc[0], rl, bb0.x); o0.y = fmaf(acc[1], rl, bb0.y);
  o0.z = fmaf(acc[2], rl, bb0.z); o0.w = fmaf(acc[3], rl, bb0.w);
  o1.x = fmaf(acc[4], rl, bb1.x); o1.y = fmaf(acc[5], rl, bb1.y);
  o1.z = fmaf(acc[6], rl, bb1.z); o1.w = fmaf(acc[7], rl, bb1.w);
  *(float4*)(out + ((size_t)v << 6) + c8) = o0;
  *(float4*)(out + ((size_t)v << 6) + c8 + 4) = o1;
}

extern "C" void kernel_launch(void* const* d_in, const int* in_sizes, int n_in,
                              void* d_out, int out_size, void* d_ws, size_t ws_size,
                              hipStream_t stream) {
  const float* x     = (const float*)d_in[0];
  const int*   ei    = (const int*)d_in[1];
  const float* Wl1   = (const float*)d_in[2];
  const float* bl1   = (const float*)d_in[3];
  const float* Wr1   = (const float*)d_in[4];
  const float* br1   = (const float*)d_in[5];
  const float* att1  = (const float*)d_in[6];
  const float* bias1 = (const float*)d_in[7];
  const float* Wl2   = (const float*)d_in[8];
  const float* bl2   = (const float*)d_in[9];
  const float* Wr2   = (const float*)d_in[10];
  const float* br2   = (const float*)d_in[11];
  const float* att2  = (const float*)d_in[12];
  const float* bias2 = (const float*)d_in[13];

  const int N  = in_sizes[0] / FIN;   // 100000
  const int E  = in_sizes[1] / 2;     // 1600000
  const int ET = E + N;
  const int NBKT = (N + BKT_SIZE - 1) >> BKT_SHIFT;   // 391 (<=512 required)

  // workspace layout
  _Float16* xl1h  = (_Float16*)d_ws;                   // N*128 f16
  _Float16* xr1h  = xl1h + (size_t)N * F1;             // N*128 f16
  _Float16* hbufh = xr1h + (size_t)N * F1;             // N*128 f16
  _Float16* Wt1l  = hbufh + (size_t)N * F1;            // 128*128 f16
  _Float16* Wt1r  = Wt1l + 128 * 128;
  _Float16* Wt2l  = Wt1r + 128 * 128;                  // 64*128 f16
  _Float16* Wt2r  = Wt2l + 64 * 128;
  int2* ind2  = (int2*)(Wt2r + 64 * 128);              // N int2
  int* csr    = (int*)(ind2 + N);                      // NBKT*BKT_CAP (padded)
  int* bcur   = csr + (size_t)NBKT * BKT_CAP;          // 512
  int* tmp    = (int*)hbufh;   // alias: NBKT*BKT_CAP ints (8MB) < N*128 f16 (25.6MB); dead before attn1 writes hbufh
  _Float16* xl2h = xl1h;                               // reuse after attn1
  _Float16* xr2h = xr1h;
  float* out  = (float*)d_out;

  const int sblocks = (ET + SCAT_CHUNK - 1) / SCAT_CHUNK;

  hipMemsetAsync(bcur, 0, 512 * sizeof(int), stream);
  bucket_scatter_kernel<<<sblocks, 256, 0, stream>>>(ei, bcur, tmp, E, ET, NBKT);
  build_csr_kernel<<<NBKT, 256, 0, stream>>>(tmp, bcur, ind2, csr, N);

  wtrans_kernel<<<dim3(64, 4), 256, 0, stream>>>(Wl1, Wr1, Wl2, Wr2, Wt1l, Wt1r, Wt2l, Wt2r);

  // layer-1 transform: reads f32 x once, produces both xl and xr (f16)
  gemm_dual_kernel<128, 2, true><<<1024, 256, 0, stream>>>(
      x, Wt1l, bl1, xl1h, Wt1r, br1, xr1h, N);

  attn1_kernel<<<(N + 15) / 16, 256, 0, stream>>>(xl1h, xr1h, att1, bias1, ind2, csr, hbufh, N);

  // layer-2 transform: reads h once, produces both xl and xr
  gemm_dual_kernel<64, 1, false><<<1024, 256, 0, stream>>>(
      hbufh, Wt2l, bl2, xl2h, Wt2r, br2, xr2h, N);

  attn2_kernel<<<(N + 31) / 32, 256, 0, stream>>>(xl2h, xr2h, att2, bias2, ind2, csr, out, N);
}

// Round 5
// 316.996 us; speedup vs baseline: 1.1441x; 1.0051x over previous
//
#include <hip/hip_runtime.h>
#include <math.h>

#define FIN 128   // input features (layer1 K, layer2 K)
#define F1  128   // H1*C1 = layer1 output width
#define C2  64    // layer2 output width
#define NEG 0.2f  // leaky_relu negative slope

#define BKT_SHIFT 8
#define BKT_SIZE  256     // nodes per bucket
#define BKT_CAP   5120    // fixed slots per bucket (mean 4348, sigma 66 -> P(overflow)~1e-31)
#define SCAT_CHUNK 4096   // edges per block in scatter (LDS image)
#define IMGCAP 8192       // LDS csr-image capacity (ints) in build_csr

typedef _Float16 half4 __attribute__((ext_vector_type(4)));
typedef _Float16 f16x8 __attribute__((ext_vector_type(8)));
typedef _Float16 h2    __attribute__((ext_vector_type(2)));
typedef float    f32x4 __attribute__((ext_vector_type(4)));

union H8u { f16x8 v; h2 p[4]; };

#if __has_builtin(__builtin_amdgcn_fdot2)
__device__ __forceinline__ float fdot2_acc(h2 a, h2 b, float c) {
  return __builtin_amdgcn_fdot2(a, b, c, false);
}
#else
__device__ __forceinline__ float fdot2_acc(h2 a, h2 b, float c) {
  return c + (float)a[0] * (float)b[0] + (float)a[1] * (float)b[1];
}
#endif

// ================= bucketed CSR build (dst-grouped, fixed-capacity buckets) =================
// Phase 1: LDS counting-sort by bucket -> per-bucket global reservation -> RUN-COALESCED copy-out.
// (Previous version did 4B scattered global writes from atomic cursors -> ~16x line amplification.)
__global__ __launch_bounds__(256) void bucket_scatter_kernel(
    const int* __restrict__ ei, int* __restrict__ bcur, int* __restrict__ tmp,
    int E, int ET, int NBKT) {
  __shared__ int sh_hist[512];
  __shared__ int sh_pref[512];
  __shared__ int sh_gbase[512];
  __shared__ int img[SCAT_CHUNK];
  __shared__ unsigned short bkt[SCAT_CHUNK];
  __shared__ int sh_tot;
  const int t = threadIdx.x;
  for (int b = t; b < NBKT; b += 256) sh_hist[b] = 0;
  if (t == 0) sh_tot = 0;
  __syncthreads();
  const int g0 = blockIdx.x * SCAT_CHUNK + t;
  int bk[16], pk[16];
#pragma unroll
  for (int i = 0; i < 16; ++i) {
    const int g = g0 + i * 256;
    int b = -1, p = 0;
    if (g < ET) {
      const int src = (g < E) ? ei[g] : (g - E);
      const int dst = (g < E) ? ei[E + g] : (g - E);
      b = dst >> BKT_SHIFT;
      p = (src << BKT_SHIFT) | (dst & (BKT_SIZE - 1));
      atomicAdd(&sh_hist[b], 1);
    }
    bk[i] = b; pk[i] = p;
  }
  __syncthreads();
  // allocate LDS range (packed, arbitrary bucket order) + global range per bucket
  for (int b = t; b < NBKT; b += 256) {
    const int c = sh_hist[b];
    if (c) {
      sh_pref[b]  = atomicAdd(&sh_tot, c);
      sh_gbase[b] = b * BKT_CAP + atomicAdd(&bcur[b], c);
    }
    sh_hist[b] = 0;   // reuse as in-block cursor
  }
  __syncthreads();
  // scatter into LDS image, grouped by bucket
#pragma unroll
  for (int i = 0; i < 16; ++i) {
    if (bk[i] >= 0) {
      const int slot = sh_pref[bk[i]] + atomicAdd(&sh_hist[bk[i]], 1);
      img[slot] = pk[i];
      bkt[slot] = (unsigned short)bk[i];
    }
  }
  __syncthreads();
  // run-coalesced copy-out: consecutive slots of one bucket -> consecutive global addrs
  const int tot = sh_tot;
  for (int j = t; j < tot; j += 256) {
    const int b = bkt[j];
    tmp[sh_gbase[b] + (j - sh_pref[b])] = img[j];
  }
}

// Per-bucket: sort by dst-local (counting sort), emit per-node {beg,end} extents.
__global__ __launch_bounds__(256) void build_csr_kernel(
    const int* __restrict__ tmp, const int* __restrict__ bcnt,
    int2* __restrict__ ind2, int* __restrict__ csr, int N) {
  __shared__ int cnt[256];
  __shared__ int cur[256];
  __shared__ int img[IMGCAP];
  const int b = blockIdx.x;
  const int t = threadIdx.x;
  const int base = b * BKT_CAP;
  const int cntb = bcnt[b];
  cnt[t] = 0;
  __syncthreads();
  for (int i = t; i < cntb; i += 256)
    atomicAdd(&cnt[tmp[base + i] & (BKT_SIZE - 1)], 1);
  __syncthreads();
  const int v = cnt[t];
  cur[t] = v;
  __syncthreads();
  for (int off = 1; off < 256; off <<= 1) {
    int val = (t >= off) ? cur[t - off] : 0;
    __syncthreads();
    cur[t] += val;
    __syncthreads();
  }
  const int excl = cur[t] - v;
  const int node = (b << BKT_SHIFT) + t;
  if (node < N) ind2[node] = make_int2(base + excl, base + excl + v);
  __syncthreads();
  cur[t] = excl;
  __syncthreads();
  if (cntb <= IMGCAP) {
    for (int i = t; i < cntb; i += 256) {
      const int p = tmp[base + i];
      const int pos = atomicAdd(&cur[p & (BKT_SIZE - 1)], 1);
      img[pos] = p >> BKT_SHIFT;
    }
    __syncthreads();
    for (int i = t; i < cntb; i += 256) csr[base + i] = img[i];
  } else {
    for (int i = t; i < cntb; i += 256) {
      const int p = tmp[base + i];
      const int pos = atomicAdd(&cur[p & (BKT_SIZE - 1)], 1);
      csr[base + pos] = p >> BKT_SHIFT;
    }
  }
}

// ---------------- weight transpose+convert: Wt[n][128] = (fp16) W[k][n] ----------------
__global__ __launch_bounds__(256) void wtrans_kernel(
    const float* __restrict__ W0, const float* __restrict__ W1,
    const float* __restrict__ W2, const float* __restrict__ W3,
    _Float16* __restrict__ T0, _Float16* __restrict__ T1,
    _Float16* __restrict__ T2, _Float16* __restrict__ T3) {
  const int m = blockIdx.y;
  const float* W = (m == 0) ? W0 : (m == 1) ? W1 : (m == 2) ? W2 : W3;
  _Float16* T = (m == 0) ? T0 : (m == 1) ? T1 : (m == 2) ? T2 : T3;
  const int ncols = (m < 2) ? 128 : 64;
  const int idx = blockIdx.x * 256 + threadIdx.x;   // over ncols*128 (n,k)
  if (idx < ncols * 128) {
    const int n = idx >> 7;
    const int k = idx & 127;
    T[idx] = (_Float16)W[k * ncols + n];
  }
}

// ---------------- dual fp16 MFMA GEMM: {OL,OR} = A[M,128] @ {WL,WR}[128,NCOLS] + b ----------------
// Reads A ONCE per row tile, computes both weight products.
// AF32: A is fp32 (layer-1 input x), converted to f16 fragments in-register.
template<int NCOLS, int CPW, bool AF32>
__global__ __launch_bounds__(256) void gemm_dual_kernel(
    const void* __restrict__ Av,
    const _Float16* __restrict__ WtL, const float* __restrict__ bLp, _Float16* __restrict__ OL,
    const _Float16* __restrict__ WtR, const float* __restrict__ bRp, _Float16* __restrict__ ORp,
    int M) {
  const int wave = threadIdx.x >> 6;
  const int lane = threadIdx.x & 63;
  const int row16 = lane & 15;
  const int quad  = lane >> 4;
  const int kb = quad * 8;
  f16x8 bfL[CPW][4], bfR[CPW][4];
  float bvL[CPW], bvR[CPW];
#pragma unroll
  for (int c = 0; c < CPW; ++c) {
    const int n0 = (wave * CPW + c) * 16;
    bvL[c] = bLp[n0 + row16];
    bvR[c] = bRp[n0 + row16];
#pragma unroll
    for (int kt = 0; kt < 4; ++kt) {
      bfL[c][kt] = *(const f16x8*)(WtL + (n0 + row16) * 128 + kt * 32 + kb);
      bfR[c][kt] = *(const f16x8*)(WtR + (n0 + row16) * 128 + kt * 32 + kb);
    }
  }
  const int rowTiles = (M + 15) >> 4;
  for (int rt = blockIdx.x; rt < rowTiles; rt += gridDim.x) {
    const int r0 = rt << 4;
    const int arow = min(r0 + row16, M - 1);
    f16x8 af[4];
    if constexpr (AF32) {
      const float4* ap = (const float4*)Av + (size_t)arow * 32;
#pragma unroll
      for (int kt = 0; kt < 4; ++kt) {
        const float4 u = ap[kt * 8 + quad * 2];
        const float4 w = ap[kt * 8 + quad * 2 + 1];
        f16x8 h;
        h[0] = (_Float16)u.x; h[1] = (_Float16)u.y;
        h[2] = (_Float16)u.z; h[3] = (_Float16)u.w;
        h[4] = (_Float16)w.x; h[5] = (_Float16)w.y;
        h[6] = (_Float16)w.z; h[7] = (_Float16)w.w;
        af[kt] = h;
      }
    } else {
      const _Float16* A = (const _Float16*)Av;
#pragma unroll
      for (int kt = 0; kt < 4; ++kt)
        af[kt] = *(const f16x8*)(A + (size_t)arow * 128 + kt * 32 + kb);
    }
    f32x4 accL[CPW], accR[CPW];
#pragma unroll
    for (int c = 0; c < CPW; ++c) {
      accL[c] = (f32x4){0.f, 0.f, 0.f, 0.f};
      accR[c] = (f32x4){0.f, 0.f, 0.f, 0.f};
    }
#pragma unroll
    for (int kt = 0; kt < 4; ++kt) {
#pragma unroll
      for (int c = 0; c < CPW; ++c) {
        accL[c] = __builtin_amdgcn_mfma_f32_16x16x32_f16(af[kt], bfL[c][kt], accL[c], 0, 0, 0);
        accR[c] = __builtin_amdgcn_mfma_f32_16x16x32_f16(af[kt], bfR[c][kt], accR[c], 0, 0, 0);
      }
    }
#pragma unroll
    for (int c = 0; c < CPW; ++c) {
      const int col = (wave * CPW + c) * 16 + row16;
#pragma unroll
      for (int r = 0; r < 4; ++r) {
        const int row = r0 + quad * 4 + r;
        if (row < M) {
          OL[(size_t)row * NCOLS + col]  = (_Float16)(accL[c][r] + bvL[c]);
          ORp[(size_t)row * NCOLS + col] = (_Float16)(accR[c][r] + bvR[c]);
        }
      }
    }
  }
}

// ---------------- attention batch: B gathers issued together, then compute ----------------
// LSH: log2 row stride in halfs (7 -> 128ch, 6 -> 64ch). XORS: shfl reduce stages.
template<int LSH, int XORS, int B>
__device__ __forceinline__ void attn_block(const _Float16* __restrict__ xlp,
                                           const int* __restrict__ csr, int e,
                                           const H8u& xru, const H8u& atu,
                                           float& l, float (&acc)[8]) {
  const h2 neg2 = {(_Float16)NEG, (_Float16)NEG};
  int s[B];
#pragma unroll
  for (int i = 0; i < B; ++i) s[i] = csr[e + i];
  H8u x[B];
#pragma unroll
  for (int i = 0; i < B; ++i) x[i].v = *(const f16x8*)(xlp + ((size_t)s[i] << LSH));
  float t[B];
#pragma unroll
  for (int i = 0; i < B; ++i) {
    float tv = 0.f;
#pragma unroll
    for (int j = 0; j < 4; ++j) {
      h2 ev = x[i].p[j] + xru.p[j];
      ev = __builtin_elementwise_max(ev, ev * neg2);
      tv = fdot2_acc(ev, atu.p[j], tv);
    }
    t[i] = tv;
  }
#pragma unroll
  for (int i = 0; i < B; ++i) {
    t[i] += __shfl_xor(t[i], 1);
    if constexpr (XORS >= 2) t[i] += __shfl_xor(t[i], 2);
    if constexpr (XORS >= 3) t[i] += __shfl_xor(t[i], 4);
  }
  float p[B];
#pragma unroll
  for (int i = 0; i < B; ++i) { p[i] = __expf(t[i]); l += p[i]; }
#pragma unroll
  for (int i = 0; i < B; ++i) {
#pragma unroll
    for (int j = 0; j < 4; ++j) {
      acc[2*j]   = fmaf(p[i], (float)x[i].p[j][0], acc[2*j]);
      acc[2*j+1] = fmaf(p[i], (float)x[i].p[j][1], acc[2*j+1]);
    }
  }
}

template<int LSH, int XORS>
__device__ __forceinline__ void attn_edges(const _Float16* __restrict__ xlp,
                                           const int* __restrict__ csr,
                                           int beg, int end,
                                           const H8u& xru, const H8u& atu,
                                           float& l, float (&acc)[8]) {
  int e = beg;
  for (; e + 4 <= end; e += 4) attn_block<LSH, XORS, 4>(xlp, csr, e, xru, atu, l, acc);
  if (e + 2 <= end) { attn_block<LSH, XORS, 2>(xlp, csr, e, xru, atu, l, acc); e += 2; }
  if (e < end)      { attn_block<LSH, XORS, 1>(xlp, csr, e, xru, atu, l, acc); }
}

// ---------------- layer 1 fused attention: 16 lanes/node x 8 chans ----------------
__global__ __launch_bounds__(256) void attn1_kernel(
    const _Float16* __restrict__ xl, const _Float16* __restrict__ xr,
    const float* __restrict__ att, const float* __restrict__ bias,
    const int2* __restrict__ ind2, const int* __restrict__ csr,
    _Float16* __restrict__ hout, int N) {
  const int lane = threadIdx.x & 15;
  const int v = blockIdx.x * 16 + (threadIdx.x >> 4);
  if (v >= N) return;
  const int c8 = lane << 3;
  const _Float16* xlp = xl + c8;
  H8u xru; xru.v = *(const f16x8*)(xr + ((size_t)v << 7) + c8);
  H8u atu;
  {
    const float4 a0 = *(const float4*)(att + c8);
    const float4 a1 = *(const float4*)(att + c8 + 4);
    f16x8 a;
    a[0] = (_Float16)a0.x; a[1] = (_Float16)a0.y; a[2] = (_Float16)a0.z; a[3] = (_Float16)a0.w;
    a[4] = (_Float16)a1.x; a[5] = (_Float16)a1.y; a[6] = (_Float16)a1.z; a[7] = (_Float16)a1.w;
    atu.v = a;
  }
  const int2 be = ind2[v];
  const int beg = be.x;
  const int end = be.y;
  float l = 0.f;
  float acc[8] = {0.f, 0.f, 0.f, 0.f, 0.f, 0.f, 0.f, 0.f};
  attn_edges<7, 1>(xlp, csr, beg, end, xru, atu, l, acc);

  const float rl = 1.f / l;
  const float4 bb0 = *(const float4*)(bias + c8);
  const float4 bb1 = *(const float4*)(bias + c8 + 4);
  float r[8];
  r[0] = fmaf(acc[0], rl, bb0.x); r[1] = fmaf(acc[1], rl, bb0.y);
  r[2] = fmaf(acc[2], rl, bb0.z); r[3] = fmaf(acc[3], rl, bb0.w);
  r[4] = fmaf(acc[4], rl, bb1.x); r[5] = fmaf(acc[5], rl, bb1.y);
  r[6] = fmaf(acc[6], rl, bb1.z); r[7] = fmaf(acc[7], rl, bb1.w);
  f16x8 hres;
#pragma unroll
  for (int i = 0; i < 8; ++i) {
    const float z = r[i] > 0.f ? r[i] : expm1f(r[i]);   // ELU
    hres[i] = (_Float16)z;
  }
  *(f16x8*)(hout + ((size_t)v << 7) + c8) = hres;
}

// ---------------- layer 2 fused attention: 8 lanes/node x 8 chans ----------------
__global__ __launch_bounds__(256) void attn2_kernel(
    const _Float16* __restrict__ xl, const _Float16* __restrict__ xr,
    const float* __restrict__ att, const float* __restrict__ bias,
    const int2* __restrict__ ind2, const int* __restrict__ csr,
    float* __restrict__ out, int N) {
  const int lane = threadIdx.x & 7;
  const int v = blockIdx.x * 32 + (threadIdx.x >> 3);
  if (v >= N) return;
  const int c8 = lane << 3;
  const _Float16* xlp = xl + c8;
  H8u xru; xru.v = *(const f16x8*)(xr + ((size_t)v << 6) + c8);
  H8u atu;
  {
    const float4 a0 = *(const float4*)(att + c8);
    const float4 a1 = *(const float4*)(att + c8 + 4);
    f16x8 a;
    a[0] = (_Float16)a0.x; a[1] = (_Float16)a0.y; a[2] = (_Float16)a0.z; a[3] = (_Float16)a0.w;
    a[4] = (_Float16)a1.x; a[5] = (_Float16)a1.y; a[6] = (_Float16)a1.z; a[7] = (_Float16)a1.w;
    atu.v = a;
  }
  const int2 be = ind2[v];
  const int beg = be.x;
  const int end = be.y;
  float l = 0.f;
  float acc[8] = {0.f, 0.f, 0.f, 0.f, 0.f, 0.f, 0.f, 0.f};
  attn_edges<6, 3>(xlp, csr, beg, end, xru, atu, l, acc);

  const float rl = 1.f / l;
  const float4 bb0 = *(const float4*)(bias + c8);
  const float4 bb1 = *(const float4*)(bias + c8 + 4);
  float4 o0, o1;
  o0.x = fmaf(acc[0], rl, bb0.x); o0.y = fmaf(acc[1], rl, bb0.y);
  o0.z = fmaf(acc[2], rl, bb0.z); o0.w = fmaf(acc[3], rl, bb0.w);
  o1.x = fmaf(acc[4], rl, bb1.x); o1.y = fmaf(acc[5], rl, bb1.y);
  o1.z = fmaf(acc[6], rl, bb1.z); o1.w = fmaf(acc[7], rl, bb1.w);
  *(float4*)(out + ((size_t)v << 6) + c8) = o0;
  *(float4*)(out + ((size_t)v << 6) + c8 + 4) = o1;
}

extern "C" void kernel_launch(void* const* d_in, const int* in_sizes, int n_in,
                              void* d_out, int out_size, void* d_ws, size_t ws_size,
                              hipStream_t stream) {
  const float* x     = (const float*)d_in[0];
  const int*   ei    = (const int*)d_in[1];
  const float* Wl1   = (const float*)d_in[2];
  const float* bl1   = (const float*)d_in[3];
  const float* Wr1   = (const float*)d_in[4];
  const float* br1   = (const float*)d_in[5];
  const float* att1  = (const float*)d_in[6];
  const float* bias1 = (const float*)d_in[7];
  const float* Wl2   = (const float*)d_in[8];
  const float* bl2   = (const float*)d_in[9];
  const float* Wr2   = (const float*)d_in[10];
  const float* br2   = (const float*)d_in[11];
  const float* att2  = (const float*)d_in[12];
  const float* bias2 = (const float*)d_in[13];

  const int N  = in_sizes[0] / FIN;   // 100000
  const int E  = in_sizes[1] / 2;     // 1600000
  const int ET = E + N;
  const int NBKT = (N + BKT_SIZE - 1) >> BKT_SHIFT;   // 391 (<=512 required)

  // workspace layout
  _Float16* xl1h  = (_Float16*)d_ws;                   // N*128 f16
  _Float16* xr1h  = xl1h + (size_t)N * F1;             // N*128 f16
  _Float16* hbufh = xr1h + (size_t)N * F1;             // N*128 f16
  _Float16* Wt1l  = hbufh + (size_t)N * F1;            // 128*128 f16
  _Float16* Wt1r  = Wt1l + 128 * 128;
  _Float16* Wt2l  = Wt1r + 128 * 128;                  // 64*128 f16
  _Float16* Wt2r  = Wt2l + 64 * 128;
  int2* ind2  = (int2*)(Wt2r + 64 * 128);              // N int2
  int* csr    = (int*)(ind2 + N);                      // NBKT*BKT_CAP (padded)
  int* bcur   = csr + (size_t)NBKT * BKT_CAP;          // 512
  int* tmp    = (int*)hbufh;   // alias: NBKT*BKT_CAP ints (8MB) < N*128 f16 (25.6MB); dead before attn1 writes hbufh
  _Float16* xl2h = xl1h;                               // reuse after attn1
  _Float16* xr2h = xr1h;
  float* out  = (float*)d_out;

  const int sblocks = (ET + SCAT_CHUNK - 1) / SCAT_CHUNK;

  hipMemsetAsync(bcur, 0, 512 * sizeof(int), stream);
  bucket_scatter_kernel<<<sblocks, 256, 0, stream>>>(ei, bcur, tmp, E, ET, NBKT);
  build_csr_kernel<<<NBKT, 256, 0, stream>>>(tmp, bcur, ind2, csr, N);

  wtrans_kernel<<<dim3(64, 4), 256, 0, stream>>>(Wl1, Wr1, Wl2, Wr2, Wt1l, Wt1r, Wt2l, Wt2r);

  // layer-1 transform: reads f32 x once, produces both xl and xr (f16)
  gemm_dual_kernel<128, 2, true><<<1024, 256, 0, stream>>>(
      x, Wt1l, bl1, xl1h, Wt1r, br1, xr1h, N);

  attn1_kernel<<<(N + 15) / 16, 256, 0, stream>>>(xl1h, xr1h, att1, bias1, ind2, csr, hbufh, N);

  // layer-2 transform: reads h once, produces both xl and xr
  gemm_dual_kernel<64, 1, false><<<1024, 256, 0, stream>>>(
      hbufh, Wt2l, bl2, xl2h, Wt2r, br2, xr2h, N);

  attn2_kernel<<<(N + 31) / 32, 256, 0, stream>>>(xl2h, xr2h, att2, bias2, ind2, csr, out, N);
}